// Round 8
// baseline (17961.139 us; speedup 1.0000x reference)
//
#include <hip/hip_runtime.h>
#include <math.h>

#define VCAB 80
#define EDIM 8
#define HDIM 256
#define BAT 2048
#define SEQ 256
#define BT 8            // batch rows per workgroup
#define NWG (BAT/BT)    // 256 workgroups = 1 per CU (grid caps occupancy at 16 waves/CU)
#define NTHR 1024       // 4 K-groups x 256 units
#define KG 4            // K-split ways

// ws layout (floats). L0 K padded 264 -> 272 so each K-quarter (68) is
// float4-aligned; pad weight rows are zero, pad input floats zeroed once.
#define W0T_KP 272
#define W1T_K 512
#define W0T_OFF 0
#define W1T_OFF (W0T_KP*1024)             // 278528
#define BIAS0_OFF (W1T_OFF + W1T_K*1024)  // 802816
#define BIAS1_OFF (BIAS0_OFF + 1024)
#define WS_FLOATS (BIAS1_OFF + 1024)      // 804864 floats ~ 3.07 MB

// Gate-interleaved transpose: WT[k][unit*4+g] = W[g*H+unit][k]
// (g in i,f,g,o order) so a float4 load at [k*1024+4*utid] = 4 gates of unit utid.
__global__ void prep_kernel(const float* __restrict__ Wih0, const float* __restrict__ Whh0,
                            const float* __restrict__ bih0, const float* __restrict__ bhh0,
                            const float* __restrict__ Wih1, const float* __restrict__ Whh1,
                            const float* __restrict__ bih1, const float* __restrict__ bhh1,
                            float* __restrict__ ws) {
  int idx = blockIdx.x * 256 + threadIdx.x;
  if (idx < W0T_KP * 1024) {
    int k = idx >> 10, n2 = idx & 1023;
    int unit = n2 >> 2, g = n2 & 3, r = g * HDIM + unit;
    float v = (k < EDIM) ? Wih0[r * EDIM + k]
            : (k < EDIM + HDIM) ? Whh0[r * HDIM + (k - EDIM)]
            : 0.f;                                   // zero pad rows 264..271
    ws[W0T_OFF + idx] = v;
  } else if (idx < W0T_KP * 1024 + W1T_K * 1024) {
    int i2 = idx - W0T_KP * 1024;
    int k = i2 >> 10, n2 = i2 & 1023;
    int unit = n2 >> 2, g = n2 & 3, r = g * HDIM + unit;
    float v = (k < HDIM) ? Wih1[r * HDIM + k] : Whh1[r * HDIM + (k - HDIM)];
    ws[W1T_OFF + i2] = v;
  } else if (idx < W0T_KP * 1024 + W1T_K * 1024 + 1024) {
    int n2 = idx - (W0T_KP * 1024 + W1T_K * 1024);
    int unit = n2 >> 2, g = n2 & 3, r = g * HDIM + unit;
    ws[BIAS0_OFF + n2] = bih0[r] + bhh0[r];
  } else if (idx < W0T_KP * 1024 + W1T_K * 1024 + 2048) {
    int n2 = idx - (W0T_KP * 1024 + W1T_K * 1024 + 1024);
    int unit = n2 >> 2, g = n2 & 3, r = g * HDIM + unit;
    ws[BIAS1_OFF + n2] = bih1[r] + bhh1[r];
  }
}

__device__ __forceinline__ float sigm(float x) {
  return 1.0f / (1.0f + __expf(-x));
}
__device__ __forceinline__ float tanh_f(float x) {
  float ax = fabsf(x);
  float e = __expf(-2.0f * ax);
  float t = 1.0f - 2.0f * e / (1.0f + e);
  return copysignf(t, x);
}

#define FMA4(A, HS, W) \
  A.x += (HS) * (W).x; A.y += (HS) * (W).y; A.z += (HS) * (W).z; A.w += (HS) * (W).w;

// One WG owns BT=8 rows for the whole sequence. 1024 threads = 4 K-groups
// (kgrp) x 256 units (utid); every thread accumulates all 8 rows over its
// K-quarter (weight stream read exactly once per WG per step - R6 lesson).
// NEW vs R7: group g OWNS rows {2g, 2g+1}: it holds their c-state (4 VGPR
// instead of 16 -> no spills) and does their activations (serial tail runs
// on 16 waves instead of 4). Partials use the diagonal-slot trick: writer w
// writes rows it doesn't own at slot w-(w>owner), so red stays 96 KB.
__global__ __launch_bounds__(NTHR, 4) void lstm_kernel(
    const int* __restrict__ x, const float* __restrict__ emb,
    const float* __restrict__ ws,
    const float* __restrict__ fcw, const float* __restrict__ fcb,
    float* __restrict__ out) {
  __shared__ float inp0[BT][W0T_KP];       // [e(8)|h0(256)|pad(8)]      8704 B
  __shared__ float inp1[BT][W1T_K];        // [h0new(256)|h1(256)]      16384 B
  __shared__ float4 red[KG - 1][BT][HDIM]; // non-owner partials        98304 B

  const int tid = threadIdx.x;
  const int utid = tid & 255;        // unit index
  const int kgrp = tid >> 8;         // K-quarter 0..3; owns rows 2k,2k+1
  const int bg = blockIdx.x * BT;
  const int r0 = 2 * kgrp;           // first owned row
  const float4* __restrict__ W0 = (const float4*)(ws + W0T_OFF);
  const float4* __restrict__ W1 = (const float4*)(ws + W1T_OFF);

  float c0[2], c1[2];                // c-state of owned rows, this unit
  c0[0] = c0[1] = c1[0] = c1[1] = 0.f;
  // zero h parts of inp0/inp1 (owned rows) + K-pad, stage emb for t=0
#pragma unroll
  for (int j = 0; j < 2; j++) {
    inp0[r0 + j][EDIM + utid] = 0.f;
    inp1[r0 + j][utid] = 0.f;
    inp1[r0 + j][HDIM + utid] = 0.f;
  }
  if (tid < BT * EDIM) {
    int b = tid >> 3, d = tid & 7;
    inp0[b][264 + d] = 0.f;                        // zero K-pad once
    int xv = x[(bg + b) * SEQ + 0];
    inp0[b][d] = emb[xv * EDIM + d];               // emb for t=0
  }
  const float4 bias0 = ((const float4*)(ws + BIAS0_OFF))[utid];
  const float4 bias1 = ((const float4*)(ws + BIAS1_OFF))[utid];
  __syncthreads();

  for (int t = 0; t < SEQ; t++) {
    // ---- layer 0 GEMM: gates[8 x 1024] = inp0[8 x 272] @ W0T, K-quarter 68
    float4 acc[BT];
#pragma unroll
    for (int b = 0; b < BT; b++) acc[b] = make_float4(0.f, 0.f, 0.f, 0.f);
    {
      const int kbase = kgrp * (W0T_KP / KG);   // 0,68,136,204 (16B-aligned)
#pragma unroll 2
      for (int i = 0; i < W0T_KP / KG / 4; i++) {  // 17 iters of 4 k-steps
        const int k = kbase + 4 * i;
        float4 wa = W0[(k + 0) * 256 + utid];
        float4 wb = W0[(k + 1) * 256 + utid];
        float4 wc = W0[(k + 2) * 256 + utid];
        float4 wd = W0[(k + 3) * 256 + utid];
#pragma unroll
        for (int b = 0; b < BT; b++) {
          float4 hv = *(const float4*)&inp0[b][k];
          FMA4(acc[b], hv.x, wa); FMA4(acc[b], hv.y, wb);
          FMA4(acc[b], hv.z, wc); FMA4(acc[b], hv.w, wd);
        }
      }
    }
#pragma unroll
    for (int r = 0; r < BT; r++) {               // deposit non-owned partials
      int o = r >> 1;
      if (o != kgrp) red[kgrp - (kgrp > o ? 1 : 0)][r][utid] = acc[r];
    }
    __syncthreads();   // B: partials visible; all inp0 reads complete

    // ---- layer 0 activation: each group does its 2 owned rows ----
#pragma unroll
    for (int j = 0; j < 2; j++) {
      int r = r0 + j;
      float4 p0 = red[0][r][utid], p1 = red[1][r][utid], p2 = red[2][r][utid];
      float gx = acc[r].x + p0.x + p1.x + p2.x + bias0.x;
      float gy = acc[r].y + p0.y + p1.y + p2.y + bias0.y;
      float gz = acc[r].z + p0.z + p1.z + p2.z + bias0.z;
      float gw = acc[r].w + p0.w + p1.w + p2.w + bias0.w;
      float ig = sigm(gx), fg = sigm(gy), gg = tanh_f(gz), og = sigm(gw);
      c0[j] = fg * c0[j] + ig * gg;
      float h = og * tanh_f(c0[j]);
      inp0[r][EDIM + utid] = h;   // h0 input for next step
      inp1[r][utid] = h;          // layer-1 input this step
    }
    if (t + 1 < SEQ && tid < BT * EDIM) {        // stage emb for t+1
      int b = tid >> 3, d = tid & 7;
      int xv = x[(bg + b) * SEQ + t + 1];
      inp0[b][d] = emb[xv * EDIM + d];
    }
    __syncthreads();   // C: h0new + next emb visible; red free for reuse

    // ---- layer 1 GEMM: gates[8 x 1024] = inp1[8 x 512] @ W1T, K-quarter 128
#pragma unroll
    for (int b = 0; b < BT; b++) acc[b] = make_float4(0.f, 0.f, 0.f, 0.f);
    {
      const int kbase = kgrp * (W1T_K / KG);   // 0,128,256,384
#pragma unroll 2
      for (int i = 0; i < W1T_K / KG / 4; i++) {  // 32 iters of 4 k-steps
        const int k = kbase + 4 * i;
        float4 wa = W1[(k + 0) * 256 + utid];
        float4 wb = W1[(k + 1) * 256 + utid];
        float4 wc = W1[(k + 2) * 256 + utid];
        float4 wd = W1[(k + 3) * 256 + utid];
#pragma unroll
        for (int b = 0; b < BT; b++) {
          float4 hv = *(const float4*)&inp1[b][k];
          FMA4(acc[b], hv.x, wa); FMA4(acc[b], hv.y, wb);
          FMA4(acc[b], hv.z, wc); FMA4(acc[b], hv.w, wd);
        }
      }
    }
#pragma unroll
    for (int r = 0; r < BT; r++) {               // deposit non-owned partials
      int o = r >> 1;
      if (o != kgrp) red[kgrp - (kgrp > o ? 1 : 0)][r][utid] = acc[r];
    }
    __syncthreads();   // D: partials visible; all inp1 reads complete

    // ---- layer 1 activation: each group does its 2 owned rows ----
#pragma unroll
    for (int j = 0; j < 2; j++) {
      int r = r0 + j;
      float4 p0 = red[0][r][utid], p1 = red[1][r][utid], p2 = red[2][r][utid];
      float gx = acc[r].x + p0.x + p1.x + p2.x + bias1.x;
      float gy = acc[r].y + p0.y + p1.y + p2.y + bias1.y;
      float gz = acc[r].z + p0.z + p1.z + p2.z + bias1.z;
      float gw = acc[r].w + p0.w + p1.w + p2.w + bias1.w;
      float ig = sigm(gx), fg = sigm(gy), gg = tanh_f(gz), og = sigm(gw);
      c1[j] = fg * c1[j] + ig * gg;
      inp1[r][HDIM + utid] = og * tanh_f(c1[j]);
    }
    __syncthreads();   // E: end of step; h1new ordered before next step reads
  }

  // ---- FC: logits[bg+b][v] = h1[b] . fcw[v] + fcb[v] ----
  for (int o = tid; o < BT * VCAB; o += NTHR) {
    int b = o / VCAB, v = o - b * VCAB;
    float a = fcb[v];
    const float4* wrow = (const float4*)(fcw + v * HDIM);
    const float4* hrow = (const float4*)&inp1[b][HDIM];
#pragma unroll 4
    for (int k = 0; k < HDIM / 4; k++) {
      float4 w = wrow[k];
      float4 h = hrow[k];
      a += h.x * w.x + h.y * w.y + h.z * w.z + h.w * w.w;
    }
    out[(bg + b) * VCAB + v] = a;
  }

  // ---- final h, c states: out layout = [logits | h(2,B,H) | c(2,B,H)] ----
  // each group writes its 2 owned rows (c lives in its registers)
  {
    float* outh = out + BAT * VCAB;
    float* outc = outh + 2 * BAT * HDIM;
#pragma unroll
    for (int j = 0; j < 2; j++) {
      int b = r0 + j;
      outh[0 * BAT * HDIM + (bg + b) * HDIM + utid] = inp0[b][EDIM + utid];
      outh[1 * BAT * HDIM + (bg + b) * HDIM + utid] = inp1[b][HDIM + utid];
      outc[0 * BAT * HDIM + (bg + b) * HDIM + utid] = c0[j];
      outc[1 * BAT * HDIM + (bg + b) * HDIM + utid] = c1[j];
    }
  }
}

extern "C" void kernel_launch(void* const* d_in, const int* in_sizes, int n_in,
                              void* d_out, int out_size, void* d_ws, size_t ws_size,
                              hipStream_t stream) {
  const int*   x    = (const int*)d_in[0];
  const float* emb  = (const float*)d_in[1];
  const float* Wih0 = (const float*)d_in[2];
  const float* Whh0 = (const float*)d_in[3];
  const float* bih0 = (const float*)d_in[4];
  const float* bhh0 = (const float*)d_in[5];
  const float* Wih1 = (const float*)d_in[6];
  const float* Whh1 = (const float*)d_in[7];
  const float* bih1 = (const float*)d_in[8];
  const float* bhh1 = (const float*)d_in[9];
  const float* fcw  = (const float*)d_in[10];
  const float* fcb  = (const float*)d_in[11];
  float* out = (float*)d_out;
  float* ws  = (float*)d_ws;

  prep_kernel<<<(WS_FLOATS + 255) / 256, 256, 0, stream>>>(
      Wih0, Whh0, bih0, bhh0, Wih1, Whh1, bih1, bhh1, ws);
  lstm_kernel<<<NWG, NTHR, 0, stream>>>(x, emb, ws, fcw, fcb, out);
}

// Round 10
// 13865.854 us; speedup vs baseline: 1.2954x; 1.2954x over previous
//
#include <hip/hip_runtime.h>
#include <math.h>

#define VCAB 80
#define EDIM 8
#define HDIM 256
#define BAT 2048
#define SEQ 256
#define BT 8            // batch rows per workgroup
#define NWG (BAT/BT)    // 256 workgroups = 1 per CU
#define NTHR 1024       // 4 K-groups x 256 units
#define KG 4            // K-split ways

// ws layout (floats). L0 K padded 264 -> 272 so each K-quarter (68) is
// float4-aligned; pad weight rows are zero, pad input floats zeroed once.
#define W0T_KP 272
#define W1T_K 512
#define W0T_OFF 0
#define W1T_OFF (W0T_KP*1024)             // 278528
#define BIAS0_OFF (W1T_OFF + W1T_K*1024)  // 802816
#define BIAS1_OFF (BIAS0_OFF + 1024)
#define WS_FLOATS (BIAS1_OFF + 1024)      // 804864 floats ~ 3.07 MB

// Gate-interleaved transpose: WT[k][unit*4+g] = W[g*H+unit][k]
// (g in i,f,g,o order) so a float4 load at [k*1024+4*utid] = 4 gates of unit utid.
__global__ void prep_kernel(const float* __restrict__ Wih0, const float* __restrict__ Whh0,
                            const float* __restrict__ bih0, const float* __restrict__ bhh0,
                            const float* __restrict__ Wih1, const float* __restrict__ Whh1,
                            const float* __restrict__ bih1, const float* __restrict__ bhh1,
                            float* __restrict__ ws) {
  int idx = blockIdx.x * 256 + threadIdx.x;
  if (idx < W0T_KP * 1024) {
    int k = idx >> 10, n2 = idx & 1023;
    int unit = n2 >> 2, g = n2 & 3, r = g * HDIM + unit;
    float v = (k < EDIM) ? Wih0[r * EDIM + k]
            : (k < EDIM + HDIM) ? Whh0[r * HDIM + (k - EDIM)]
            : 0.f;                                   // zero pad rows 264..271
    ws[W0T_OFF + idx] = v;
  } else if (idx < W0T_KP * 1024 + W1T_K * 1024) {
    int i2 = idx - W0T_KP * 1024;
    int k = i2 >> 10, n2 = i2 & 1023;
    int unit = n2 >> 2, g = n2 & 3, r = g * HDIM + unit;
    float v = (k < HDIM) ? Wih1[r * HDIM + k] : Whh1[r * HDIM + (k - HDIM)];
    ws[W1T_OFF + i2] = v;
  } else if (idx < W0T_KP * 1024 + W1T_K * 1024 + 1024) {
    int n2 = idx - (W0T_KP * 1024 + W1T_K * 1024);
    int unit = n2 >> 2, g = n2 & 3, r = g * HDIM + unit;
    ws[BIAS0_OFF + n2] = bih0[r] + bhh0[r];
  } else if (idx < W0T_KP * 1024 + W1T_K * 1024 + 2048) {
    int n2 = idx - (W0T_KP * 1024 + W1T_K * 1024 + 1024);
    int unit = n2 >> 2, g = n2 & 3, r = g * HDIM + unit;
    ws[BIAS1_OFF + n2] = bih1[r] + bhh1[r];
  }
}

__device__ __forceinline__ float sigm(float x) {
  return 1.0f / (1.0f + __expf(-x));
}
__device__ __forceinline__ float tanh_f(float x) {
  float ax = fabsf(x);
  float e = __expf(-2.0f * ax);
  float t = 1.0f - 2.0f * e / (1.0f + e);
  return copysignf(t, x);
}

#define FMA4(A, HS, W) \
  A.x += (HS) * (W).x; A.y += (HS) * (W).y; A.z += (HS) * (W).z; A.w += (HS) * (W).w;

// One WG owns BT=8 rows for the whole sequence. 1024 threads = 4 K-groups
// (kgrp) x 256 units (utid); every thread accumulates all 8 rows over its
// K-quarter (weight stream read exactly once per WG per step - R6 lesson).
// Group g owns rows {2g,2g+1}: holds their c-state + does their activations.
// R8 lesson (rule #20): NEVER index a register array with a runtime value --
// owned accs are extracted via a wave-uniform branch with CONSTANT indices;
// acc[] is only ever indexed by unrolled compile-time constants.
__global__ __launch_bounds__(NTHR, 4) void lstm_kernel(
    const int* __restrict__ x, const float* __restrict__ emb,
    const float* __restrict__ ws,
    const float* __restrict__ fcw, const float* __restrict__ fcb,
    float* __restrict__ out) {
  __shared__ float inp0[BT][W0T_KP];       // [e(8)|h0(256)|pad(8)]      8704 B
  __shared__ float inp1[BT][W1T_K];        // [h0new(256)|h1(256)]      16384 B
  __shared__ float4 red[KG - 1][BT][HDIM]; // non-owner partials        98304 B

  const int tid = threadIdx.x;
  const int utid = tid & 255;        // unit index
  const int kgrp = tid >> 8;         // K-quarter 0..3; owns rows 2k,2k+1
  const int bg = blockIdx.x * BT;
  const int r0 = 2 * kgrp;           // first owned row (LDS/global addr only!)
  const float4* __restrict__ W0 = (const float4*)(ws + W0T_OFF);
  const float4* __restrict__ W1 = (const float4*)(ws + W1T_OFF);

  float c0[2], c1[2];                // c-state of owned rows, this unit
  c0[0] = c0[1] = c1[0] = c1[1] = 0.f;
#pragma unroll
  for (int j = 0; j < 2; j++) {
    inp0[r0 + j][EDIM + utid] = 0.f;
    inp1[r0 + j][utid] = 0.f;
    inp1[r0 + j][HDIM + utid] = 0.f;
  }
  if (tid < BT * EDIM) {
    int b = tid >> 3, d = tid & 7;
    inp0[b][264 + d] = 0.f;                        // zero K-pad once
    int xv = x[(bg + b) * SEQ + 0];
    inp0[b][d] = emb[xv * EDIM + d];               // emb for t=0
  }
  const float4 bias0 = ((const float4*)(ws + BIAS0_OFF))[utid];
  const float4 bias1 = ((const float4*)(ws + BIAS1_OFF))[utid];
  __syncthreads();

  // extracts acc[2*kgrp], acc[2*kgrp+1] with COMPILE-TIME indices
#define EXTRACT_OWN(own, acc)                                   \
  if (kgrp == 0)      { own[0] = acc[0]; own[1] = acc[1]; }     \
  else if (kgrp == 1) { own[0] = acc[2]; own[1] = acc[3]; }     \
  else if (kgrp == 2) { own[0] = acc[4]; own[1] = acc[5]; }     \
  else                { own[0] = acc[6]; own[1] = acc[7]; }

  for (int t = 0; t < SEQ; t++) {
    // ---- layer 0 GEMM: gates[8 x 1024] = inp0[8 x 272] @ W0T, K-quarter 68
    float4 acc[BT];
#pragma unroll
    for (int b = 0; b < BT; b++) acc[b] = make_float4(0.f, 0.f, 0.f, 0.f);
    {
      const int kbase = kgrp * (W0T_KP / KG);   // 0,68,136,204 (16B-aligned)
#pragma unroll 2
      for (int i = 0; i < W0T_KP / KG / 4; i++) {  // 17 iters of 4 k-steps
        const int k = kbase + 4 * i;
        float4 wa = W0[(k + 0) * 256 + utid];
        float4 wb = W0[(k + 1) * 256 + utid];
        float4 wc = W0[(k + 2) * 256 + utid];
        float4 wd = W0[(k + 3) * 256 + utid];
#pragma unroll
        for (int b = 0; b < BT; b++) {
          float4 hv = *(const float4*)&inp0[b][k];
          FMA4(acc[b], hv.x, wa); FMA4(acc[b], hv.y, wb);
          FMA4(acc[b], hv.z, wc); FMA4(acc[b], hv.w, wd);
        }
      }
    }
    float4 own[2];
    EXTRACT_OWN(own, acc)
#pragma unroll
    for (int r = 0; r < BT; r++) {               // deposit non-owned partials
      int o = r >> 1;                            // acc[r]: constant index
      if (o != kgrp) red[kgrp - (kgrp > o ? 1 : 0)][r][utid] = acc[r];
    }
    __syncthreads();   // B: partials visible; all inp0 reads complete

    // ---- layer 0 activation: each group does its 2 owned rows ----
#pragma unroll
    for (int j = 0; j < 2; j++) {
      int r = r0 + j;                            // LDS address only
      float4 p0 = red[0][r][utid], p1 = red[1][r][utid], p2 = red[2][r][utid];
      float gx = own[j].x + p0.x + p1.x + p2.x + bias0.x;
      float gy = own[j].y + p0.y + p1.y + p2.y + bias0.y;
      float gz = own[j].z + p0.z + p1.z + p2.z + bias0.z;
      float gw = own[j].w + p0.w + p1.w + p2.w + bias0.w;
      float ig = sigm(gx), fg = sigm(gy), gg = tanh_f(gz), og = sigm(gw);
      c0[j] = fg * c0[j] + ig * gg;
      float h = og * tanh_f(c0[j]);
      inp0[r][EDIM + utid] = h;   // h0 input for next step
      inp1[r][utid] = h;          // layer-1 input this step
    }
    if (t + 1 < SEQ && tid < BT * EDIM) {        // stage emb for t+1
      int b = tid >> 3, d = tid & 7;
      int xv = x[(bg + b) * SEQ + t + 1];
      inp0[b][d] = emb[xv * EDIM + d];
    }
    __syncthreads();   // C: h0new + next emb visible; red free for reuse

    // ---- layer 1 GEMM: gates[8 x 1024] = inp1[8 x 512] @ W1T, K-quarter 128
#pragma unroll
    for (int b = 0; b < BT; b++) acc[b] = make_float4(0.f, 0.f, 0.f, 0.f);
    {
      const int kbase = kgrp * (W1T_K / KG);   // 0,128,256,384
#pragma unroll 2
      for (int i = 0; i < W1T_K / KG / 4; i++) {  // 32 iters of 4 k-steps
        const int k = kbase + 4 * i;
        float4 wa = W1[(k + 0) * 256 + utid];
        float4 wb = W1[(k + 1) * 256 + utid];
        float4 wc = W1[(k + 2) * 256 + utid];
        float4 wd = W1[(k + 3) * 256 + utid];
#pragma unroll
        for (int b = 0; b < BT; b++) {
          float4 hv = *(const float4*)&inp1[b][k];
          FMA4(acc[b], hv.x, wa); FMA4(acc[b], hv.y, wb);
          FMA4(acc[b], hv.z, wc); FMA4(acc[b], hv.w, wd);
        }
      }
    }
    EXTRACT_OWN(own, acc)
#pragma unroll
    for (int r = 0; r < BT; r++) {               // deposit non-owned partials
      int o = r >> 1;
      if (o != kgrp) red[kgrp - (kgrp > o ? 1 : 0)][r][utid] = acc[r];
    }
    __syncthreads();   // D: partials visible; all inp1 reads complete

    // ---- layer 1 activation: each group does its 2 owned rows ----
#pragma unroll
    for (int j = 0; j < 2; j++) {
      int r = r0 + j;
      float4 p0 = red[0][r][utid], p1 = red[1][r][utid], p2 = red[2][r][utid];
      float gx = own[j].x + p0.x + p1.x + p2.x + bias1.x;
      float gy = own[j].y + p0.y + p1.y + p2.y + bias1.y;
      float gz = own[j].z + p0.z + p1.z + p2.z + bias1.z;
      float gw = own[j].w + p0.w + p1.w + p2.w + bias1.w;
      float ig = sigm(gx), fg = sigm(gy), gg = tanh_f(gz), og = sigm(gw);
      c1[j] = fg * c1[j] + ig * gg;
      inp1[r][HDIM + utid] = og * tanh_f(c1[j]);
    }
    __syncthreads();   // E: end of step; h1new ordered before next step reads
  }

  // ---- FC: logits[bg+b][v] = h1[b] . fcw[v] + fcb[v] ----
  for (int o = tid; o < BT * VCAB; o += NTHR) {
    int b = o / VCAB, v = o - b * VCAB;
    float a = fcb[v];
    const float4* wrow = (const float4*)(fcw + v * HDIM);
    const float4* hrow = (const float4*)&inp1[b][HDIM];
#pragma unroll 4
    for (int k = 0; k < HDIM / 4; k++) {
      float4 w = wrow[k];
      float4 h = hrow[k];
      a += h.x * w.x + h.y * w.y + h.z * w.z + h.w * w.w;
    }
    out[(bg + b) * VCAB + v] = a;
  }

  // ---- final h, c states: out layout = [logits | h(2,B,H) | c(2,B,H)] ----
  // each group writes its 2 owned rows (c lives in its registers)
  {
    float* outh = out + BAT * VCAB;
    float* outc = outh + 2 * BAT * HDIM;
#pragma unroll
    for (int j = 0; j < 2; j++) {
      int b = r0 + j;
      outh[0 * BAT * HDIM + (bg + b) * HDIM + utid] = inp0[b][EDIM + utid];
      outh[1 * BAT * HDIM + (bg + b) * HDIM + utid] = inp1[b][HDIM + utid];
      outc[0 * BAT * HDIM + (bg + b) * HDIM + utid] = c0[j];
      outc[1 * BAT * HDIM + (bg + b) * HDIM + utid] = c1[j];
    }
  }
}

extern "C" void kernel_launch(void* const* d_in, const int* in_sizes, int n_in,
                              void* d_out, int out_size, void* d_ws, size_t ws_size,
                              hipStream_t stream) {
  const int*   x    = (const int*)d_in[0];
  const float* emb  = (const float*)d_in[1];
  const float* Wih0 = (const float*)d_in[2];
  const float* Whh0 = (const float*)d_in[3];
  const float* bih0 = (const float*)d_in[4];
  const float* bhh0 = (const float*)d_in[5];
  const float* Wih1 = (const float*)d_in[6];
  const float* Whh1 = (const float*)d_in[7];
  const float* bih1 = (const float*)d_in[8];
  const float* bhh1 = (const float*)d_in[9];
  const float* fcw  = (const float*)d_in[10];
  const float* fcb  = (const float*)d_in[11];
  float* out = (float*)d_out;
  float* ws  = (float*)d_ws;

  prep_kernel<<<(WS_FLOATS + 255) / 256, 256, 0, stream>>>(
      Wih0, Whh0, bih0, bhh0, Wih1, Whh1, bih1, bhh1, ws);
  lstm_kernel<<<NWG, NTHR, 0, stream>>>(x, emb, ws, fcw, fcb, out);
}

// Round 15
// 13556.265 us; speedup vs baseline: 1.3249x; 1.0228x over previous
//
#include <hip/hip_runtime.h>
#include <math.h>

#define VCAB 80
#define EDIM 8
#define HDIM 256
#define BAT 2048
#define SEQ 256
#define BT 8            // batch rows per workgroup
#define NWG (BAT/BT)    // 256 workgroups = 1 per CU
#define NTHR 1024       // 4 K-groups x 256 units
#define KG 4            // K-split ways

// ws layout (floats). L0 K padded 264 -> 272 so each K-quarter (68) is
// float4-aligned; pad weight rows are zero, pad input floats zeroed once.
#define W0T_KP 272
#define W1T_K 512
#define W0T_OFF 0
#define W1T_OFF (W0T_KP*1024)             // 278528
#define BIAS0_OFF (W1T_OFF + W1T_K*1024)  // 802816
#define BIAS1_OFF (BIAS0_OFF + 1024)
#define WS_FLOATS (BIAS1_OFF + 1024)      // 804864 floats ~ 3.07 MB

// Gate-interleaved transpose: WT[k][unit*4+g] = W[g*H+unit][k]
// (g in i,f,g,o order) so a float4 load at [k*1024+4*utid] = 4 gates of unit utid.
__global__ void prep_kernel(const float* __restrict__ Wih0, const float* __restrict__ Whh0,
                            const float* __restrict__ bih0, const float* __restrict__ bhh0,
                            const float* __restrict__ Wih1, const float* __restrict__ Whh1,
                            const float* __restrict__ bih1, const float* __restrict__ bhh1,
                            float* __restrict__ ws) {
  int idx = blockIdx.x * 256 + threadIdx.x;
  if (idx < W0T_KP * 1024) {
    int k = idx >> 10, n2 = idx & 1023;
    int unit = n2 >> 2, g = n2 & 3, r = g * HDIM + unit;
    float v = (k < EDIM) ? Wih0[r * EDIM + k]
            : (k < EDIM + HDIM) ? Whh0[r * HDIM + (k - EDIM)]
            : 0.f;                                   // zero pad rows 264..271
    ws[W0T_OFF + idx] = v;
  } else if (idx < W0T_KP * 1024 + W1T_K * 1024) {
    int i2 = idx - W0T_KP * 1024;
    int k = i2 >> 10, n2 = i2 & 1023;
    int unit = n2 >> 2, g = n2 & 3, r = g * HDIM + unit;
    float v = (k < HDIM) ? Wih1[r * HDIM + k] : Whh1[r * HDIM + (k - HDIM)];
    ws[W1T_OFF + i2] = v;
  } else if (idx < W0T_KP * 1024 + W1T_K * 1024 + 1024) {
    int n2 = idx - (W0T_KP * 1024 + W1T_K * 1024);
    int unit = n2 >> 2, g = n2 & 3, r = g * HDIM + unit;
    ws[BIAS0_OFF + n2] = bih0[r] + bhh0[r];
  } else if (idx < W0T_KP * 1024 + W1T_K * 1024 + 2048) {
    int n2 = idx - (W0T_KP * 1024 + W1T_K * 1024 + 1024);
    int unit = n2 >> 2, g = n2 & 3, r = g * HDIM + unit;
    ws[BIAS1_OFF + n2] = bih1[r] + bhh1[r];
  }
}

__device__ __forceinline__ float sigm(float x) {
  return 1.0f / (1.0f + __expf(-x));
}
__device__ __forceinline__ float tanh_f(float x) {
  float ax = fabsf(x);
  float e = __expf(-2.0f * ax);
  float t = 1.0f - 2.0f * e / (1.0f + e);
  return copysignf(t, x);
}

#define FMA4(A, HS, W) \
  A.x += (HS) * (W).x; A.y += (HS) * (W).y; A.z += (HS) * (W).z; A.w += (HS) * (W).w;

// One WG owns BT=8 rows for the whole sequence. 1024 threads = 4 K-groups
// (kgrp) x 256 units (utid); every thread accumulates all 8 rows over its
// K-quarter (weight stream read exactly once per WG per step - R6 lesson).
// Group g owns rows {2g,2g+1}: holds their c-state + does their activations.
// R8 lesson (rule #20): acc[] only ever indexed by compile-time constants;
// owned accs extracted via wave-uniform branch (EXTRACT_OWN).
// R10 lesson: __launch_bounds__(.,4) capped VGPR at 64 -> acc[8] spilled to
// scratch (5.4GB FETCH + 1.4GB WRITE). Occupancy is grid+LDS-fixed at
// 1 WG/CU (= 4 waves/EU) regardless of VGPR count (4 x 512 fits the 2048
// pool), so declare min 1 wave/EU to unlock the full register budget.
__global__ __launch_bounds__(NTHR, 1) void lstm_kernel(
    const int* __restrict__ x, const float* __restrict__ emb,
    const float* __restrict__ ws,
    const float* __restrict__ fcw, const float* __restrict__ fcb,
    float* __restrict__ out) {
  __shared__ float inp0[BT][W0T_KP];       // [e(8)|h0(256)|pad(8)]      8704 B
  __shared__ float inp1[BT][W1T_K];        // [h0new(256)|h1(256)]      16384 B
  __shared__ float4 red[KG - 1][BT][HDIM]; // non-owner partials        98304 B

  const int tid = threadIdx.x;
  const int utid = tid & 255;        // unit index
  const int kgrp = tid >> 8;         // K-quarter 0..3; owns rows 2k,2k+1 (wave-uniform)
  const int bg = blockIdx.x * BT;
  const int r0 = 2 * kgrp;           // first owned row (LDS/global addr only!)
  const float4* __restrict__ W0 = (const float4*)(ws + W0T_OFF);
  const float4* __restrict__ W1 = (const float4*)(ws + W1T_OFF);

  float c0[2], c1[2];                // c-state of owned rows, this unit
  c0[0] = c0[1] = c1[0] = c1[1] = 0.f;
#pragma unroll
  for (int j = 0; j < 2; j++) {
    inp0[r0 + j][EDIM + utid] = 0.f;
    inp1[r0 + j][utid] = 0.f;
    inp1[r0 + j][HDIM + utid] = 0.f;
  }
  if (tid < BT * EDIM) {
    int b = tid >> 3, d = tid & 7;
    inp0[b][264 + d] = 0.f;                        // zero K-pad once
    int xv = x[(bg + b) * SEQ + 0];
    inp0[b][d] = emb[xv * EDIM + d];               // emb for t=0
  }
  const float4 bias0 = ((const float4*)(ws + BIAS0_OFF))[utid];
  const float4 bias1 = ((const float4*)(ws + BIAS1_OFF))[utid];
  __syncthreads();

  // extracts acc[2*kgrp], acc[2*kgrp+1] with COMPILE-TIME indices
#define EXTRACT_OWN(own, acc)                                   \
  if (kgrp == 0)      { own[0] = acc[0]; own[1] = acc[1]; }     \
  else if (kgrp == 1) { own[0] = acc[2]; own[1] = acc[3]; }     \
  else if (kgrp == 2) { own[0] = acc[4]; own[1] = acc[5]; }     \
  else                { own[0] = acc[6]; own[1] = acc[7]; }

  for (int t = 0; t < SEQ; t++) {
    // ---- layer 0 GEMM: gates[8 x 1024] = inp0[8 x 272] @ W0T, K-quarter 68
    float4 acc[BT];
#pragma unroll
    for (int b = 0; b < BT; b++) acc[b] = make_float4(0.f, 0.f, 0.f, 0.f);
    {
      const int kbase = kgrp * (W0T_KP / KG);   // 0,68,136,204 (16B-aligned)
#pragma unroll 2
      for (int i = 0; i < W0T_KP / KG / 4; i++) {  // 17 iters of 4 k-steps
        const int k = kbase + 4 * i;
        float4 wa = W0[(k + 0) * 256 + utid];
        float4 wb = W0[(k + 1) * 256 + utid];
        float4 wc = W0[(k + 2) * 256 + utid];
        float4 wd = W0[(k + 3) * 256 + utid];
#pragma unroll
        for (int b = 0; b < BT; b++) {
          float4 hv = *(const float4*)&inp0[b][k];
          FMA4(acc[b], hv.x, wa); FMA4(acc[b], hv.y, wb);
          FMA4(acc[b], hv.z, wc); FMA4(acc[b], hv.w, wd);
        }
      }
    }
    float4 own[2];
    EXTRACT_OWN(own, acc)
#pragma unroll
    for (int r = 0; r < BT; r++) {               // deposit non-owned partials
      int o = r >> 1;                            // acc[r]: constant index
      if (o != kgrp) red[kgrp - (kgrp > o ? 1 : 0)][r][utid] = acc[r];
    }
    __syncthreads();   // B: partials visible; all inp0 reads complete

    // ---- layer 0 activation: each group does its 2 owned rows ----
#pragma unroll
    for (int j = 0; j < 2; j++) {
      int r = r0 + j;                            // LDS address only
      float4 p0 = red[0][r][utid], p1 = red[1][r][utid], p2 = red[2][r][utid];
      float gx = own[j].x + p0.x + p1.x + p2.x + bias0.x;
      float gy = own[j].y + p0.y + p1.y + p2.y + bias0.y;
      float gz = own[j].z + p0.z + p1.z + p2.z + bias0.z;
      float gw = own[j].w + p0.w + p1.w + p2.w + bias0.w;
      float ig = sigm(gx), fg = sigm(gy), gg = tanh_f(gz), og = sigm(gw);
      c0[j] = fg * c0[j] + ig * gg;
      float h = og * tanh_f(c0[j]);
      inp0[r][EDIM + utid] = h;   // h0 input for next step
      inp1[r][utid] = h;          // layer-1 input this step
    }
    if (t + 1 < SEQ && tid < BT * EDIM) {        // stage emb for t+1
      int b = tid >> 3, d = tid & 7;
      int xv = x[(bg + b) * SEQ + t + 1];
      inp0[b][d] = emb[xv * EDIM + d];
    }
    __syncthreads();   // C: h0new + next emb visible; red free for reuse

    // ---- layer 1 GEMM: gates[8 x 1024] = inp1[8 x 512] @ W1T, K-quarter 128
#pragma unroll
    for (int b = 0; b < BT; b++) acc[b] = make_float4(0.f, 0.f, 0.f, 0.f);
    {
      const int kbase = kgrp * (W1T_K / KG);   // 0,128,256,384
#pragma unroll 2
      for (int i = 0; i < W1T_K / KG / 4; i++) {  // 32 iters of 4 k-steps
        const int k = kbase + 4 * i;
        float4 wa = W1[(k + 0) * 256 + utid];
        float4 wb = W1[(k + 1) * 256 + utid];
        float4 wc = W1[(k + 2) * 256 + utid];
        float4 wd = W1[(k + 3) * 256 + utid];
#pragma unroll
        for (int b = 0; b < BT; b++) {
          float4 hv = *(const float4*)&inp1[b][k];
          FMA4(acc[b], hv.x, wa); FMA4(acc[b], hv.y, wb);
          FMA4(acc[b], hv.z, wc); FMA4(acc[b], hv.w, wd);
        }
      }
    }
    EXTRACT_OWN(own, acc)
#pragma unroll
    for (int r = 0; r < BT; r++) {               // deposit non-owned partials
      int o = r >> 1;
      if (o != kgrp) red[kgrp - (kgrp > o ? 1 : 0)][r][utid] = acc[r];
    }
    __syncthreads();   // D: partials visible; all inp1 reads complete

    // ---- layer 1 activation: each group does its 2 owned rows ----
#pragma unroll
    for (int j = 0; j < 2; j++) {
      int r = r0 + j;
      float4 p0 = red[0][r][utid], p1 = red[1][r][utid], p2 = red[2][r][utid];
      float gx = own[j].x + p0.x + p1.x + p2.x + bias1.x;
      float gy = own[j].y + p0.y + p1.y + p2.y + bias1.y;
      float gz = own[j].z + p0.z + p1.z + p2.z + bias1.z;
      float gw = own[j].w + p0.w + p1.w + p2.w + bias1.w;
      float ig = sigm(gx), fg = sigm(gy), gg = tanh_f(gz), og = sigm(gw);
      c1[j] = fg * c1[j] + ig * gg;
      inp1[r][HDIM + utid] = og * tanh_f(c1[j]);
    }
    __syncthreads();   // E: end of step; h1new ordered before next step reads
  }

  // ---- FC: logits[bg+b][v] = h1[b] . fcw[v] + fcb[v] ----
  for (int o = tid; o < BT * VCAB; o += NTHR) {
    int b = o / VCAB, v = o - b * VCAB;
    float a = fcb[v];
    const float4* wrow = (const float4*)(fcw + v * HDIM);
    const float4* hrow = (const float4*)&inp1[b][HDIM];
#pragma unroll 4
    for (int k = 0; k < HDIM / 4; k++) {
      float4 w = wrow[k];
      float4 h = hrow[k];
      a += h.x * w.x + h.y * w.y + h.z * w.z + h.w * w.w;
    }
    out[(bg + b) * VCAB + v] = a;
  }

  // ---- final h, c states: out layout = [logits | h(2,B,H) | c(2,B,H)] ----
  // each group writes its 2 owned rows (c lives in its registers)
  {
    float* outh = out + BAT * VCAB;
    float* outc = outh + 2 * BAT * HDIM;
#pragma unroll
    for (int j = 0; j < 2; j++) {
      int b = r0 + j;
      outh[0 * BAT * HDIM + (bg + b) * HDIM + utid] = inp0[b][EDIM + utid];
      outh[1 * BAT * HDIM + (bg + b) * HDIM + utid] = inp1[b][HDIM + utid];
      outc[0 * BAT * HDIM + (bg + b) * HDIM + utid] = c0[j];
      outc[1 * BAT * HDIM + (bg + b) * HDIM + utid] = c1[j];
    }
  }
}

extern "C" void kernel_launch(void* const* d_in, const int* in_sizes, int n_in,
                              void* d_out, int out_size, void* d_ws, size_t ws_size,
                              hipStream_t stream) {
  const int*   x    = (const int*)d_in[0];
  const float* emb  = (const float*)d_in[1];
  const float* Wih0 = (const float*)d_in[2];
  const float* Whh0 = (const float*)d_in[3];
  const float* bih0 = (const float*)d_in[4];
  const float* bhh0 = (const float*)d_in[5];
  const float* Wih1 = (const float*)d_in[6];
  const float* Whh1 = (const float*)d_in[7];
  const float* bih1 = (const float*)d_in[8];
  const float* bhh1 = (const float*)d_in[9];
  const float* fcw  = (const float*)d_in[10];
  const float* fcb  = (const float*)d_in[11];
  float* out = (float*)d_out;
  float* ws  = (float*)d_ws;

  prep_kernel<<<(WS_FLOATS + 255) / 256, 256, 0, stream>>>(
      Wih0, Whh0, bih0, bhh0, Wih1, Whh1, bih1, bhh1, ws);
  lstm_kernel<<<NWG, NTHR, 0, stream>>>(x, emb, ws, fcw, fcb, out);
}